// Round 12
// baseline (132.353 us; speedup 1.0000x reference)
//
#include <hip/hip_runtime.h>
#include <hip/hip_bf16.h>
#include <stdint.h>

using bf16 = __hip_bfloat16;
typedef __attribute__((ext_vector_type(8))) short bf16x8;   // 8 bf16 = 4 VGPRs
typedef __attribute__((ext_vector_type(4))) float f32x4;

static __device__ __forceinline__ float b2f(short u) {
  union { float f; unsigned int i; } c;
  c.i = ((unsigned int)(unsigned short)u) << 16;
  return c.f;
}
static __device__ __forceinline__ short f2b(float f) {
  return (short)__bfloat16_as_ushort(__float2bfloat16(f));
}

static __device__ __forceinline__ void cfence() { asm volatile("" ::: "memory"); }
static __device__ __forceinline__ void bar()    { cfence(); __builtin_amdgcn_s_barrier(); cfence(); }

__device__ __forceinline__ void async16(const void* g, void* lds) {
  __builtin_amdgcn_global_load_lds(
      (const __attribute__((address_space(1))) void*)g,
      (__attribute__((address_space(3))) void*)lds, 16, 0, 0);
}

// ---------------------------------------------------------------------------
// Both Kron-expanded transposed weights in one dispatch.
// ---------------------------------------------------------------------------
__global__ void build_w(const float* __restrict__ phm,
                        const float* __restrict__ Wd,
                        const float* __restrict__ Wu,
                        bf16* __restrict__ wdT, bf16* __restrict__ wuT) {
  int idx = blockIdx.x * 256 + threadIdx.x;
  if (idx < 1024 * 1024) {
    int n = idx >> 11, k = idx & 2047;
    int r = n >> 7, s = n & 127;
    int p = k >> 9, q = k & 511;
    float v = 0.f;
#pragma unroll
    for (int i = 0; i < 4; ++i)
      v += phm[i * 16 + p * 4 + r] * Wd[i * 65536 + q * 128 + s];
    wdT[idx] = (bf16)v;
  } else {
    int jj = idx - 1024 * 1024;
    int d = jj >> 9, b = jj & 511;
    int r = d >> 9, s = d & 511;
    int p = b >> 7, q = b & 127;
    float v = 0.f;
#pragma unroll
    for (int i = 0; i < 4; ++i)
      v += phm[i * 16 + p * 4 + r] * Wu[i * 65536 + q * 512 + s];
    wuT[jj] = (bf16)v;
  }
}

// ---------------------------------------------------------------------------
// GEMM1 fused cast, split-K x4:  P[ch] = x(f32) @ wdT^T + bd/4
// (bias/4 folded into each partial so Sum_c P_c carries the full bias.)
// BM=128, BN=512 (x read exactly ONCE), BK=64, chunk K=512. R9 structure.
// ---------------------------------------------------------------------------
__global__ __launch_bounds__(512, 2)
void gemm1f(const float* __restrict__ X, const bf16* __restrict__ Wt,
            const float* __restrict__ bd, bf16* __restrict__ P) {
  constexpr int BK = 64, KTOT = 2048, NOUT = 512;
  __shared__ bf16 Ash[128 * 64];          // 16 KB (single buffer)
  __shared__ bf16 Bsh[2][2][256 * 64];    // 128 KB

  const int xcd = blockIdx.x & 7, w = blockIdx.x >> 3;
  const int bx = xcd * 8 + (w & 7);       // 0..63 row tile
  const int ch = w >> 3;                  // 0..3 K chunk
  const int bm = bx * 128;
  const int koff = ch * 512;
  bf16* __restrict__ Pc = P + (size_t)ch * (8192 * NOUT);

  const int tid  = threadIdx.x;           // 0..511
  const int lane = tid & 63;
  const int wave = tid >> 6;
  const int wm   = (wave >> 2) * 64;      // 2 M groups
  const int wnn  = (wave & 3) * 128;      // 4 N groups of 128
  const int hB   = wnn >> 8;              // B half
  const int bb   = wnn & 255;             // row base within half (0 or 128)
  const int rl   = lane & 15;
  const int sw   = lane >> 4;
  const int sx   = rl & 7;

  const int arow = tid >> 2;
  const int ac0  = (tid & 3) * 16;
  const float* __restrict__ Xrow = X + (size_t)(bm + arow) * KTOT + koff + ac0;
  const int as0 = (tid & 3) * 2;

  f32x4 acc[4][8] = {};
  float4 av[4];

#define ISSUE_AV(tt)                                                          \
  { _Pragma("unroll")                                                         \
    for (int q = 0; q < 4; ++q)                                               \
      av[q] = *(const float4*)(Xrow + (size_t)(tt) * BK + q * 4); }

#define WRITE_A()                                                             \
  {                                                                           \
    bf16x8 w0, w1;                                                            \
    _Pragma("unroll")                                                         \
    for (int e = 0; e < 4; ++e) {                                             \
      w0[e]     = f2b(((const float*)&av[0])[e]);                             \
      w0[e + 4] = f2b(((const float*)&av[1])[e]);                             \
      w1[e]     = f2b(((const float*)&av[2])[e]);                             \
      w1[e + 4] = f2b(((const float*)&av[3])[e]);                             \
    }                                                                         \
    *(bf16x8*)(&Ash[arow * 64 + ((as0 ^ (arow & 7)) * 8)]) = w0;              \
    *(bf16x8*)(&Ash[arow * 64 + (((as0 + 1) ^ (arow & 7)) * 8)]) = w1;        \
  }

#define STAGE_BH(tt, h)                                                       \
  { _Pragma("unroll")                                                         \
    for (int is = 0; is < 4; ++is) {                                          \
      int idx = is * 512 + tid;                                               \
      int r = idx >> 3, sl = idx & 7;                                         \
      async16(Wt + (size_t)((h) * 256 + r) * KTOT + koff + (tt) * BK          \
                  + ((sl ^ (r & 7)) * 8),                                     \
              &Bsh[(tt) & 1][h][idx * 8]);                                    \
    } }

  const int nt = 512 / BK;   // 8

  ISSUE_AV(0);
  STAGE_BH(0, 0); STAGE_BH(0, 1);
  asm volatile("s_waitcnt vmcnt(8)" ::: "memory");
  WRITE_A();
  ISSUE_AV(1);
  asm volatile("s_waitcnt vmcnt(4) lgkmcnt(0)" ::: "memory");
  bar();

  bf16x8 af[4][2], bfr[2][2];

  for (int t = 0; t < nt; ++t) {
    const int cur = t & 1;
    const bf16* __restrict__ Bcur = &Bsh[cur][hB][0];

#define LDAF(m, ks) af[m][ks] = *(const bf16x8*)(&Ash[(wm + (m)*16 + rl) * 64 + ((((ks)*4 + sw) ^ sx) * 8)])
#define LDBF(q, n, ks) bfr[q][ks] = *(const bf16x8*)(Bcur + (bb + (n)*16 + rl) * 64 + ((((ks)*4 + sw) ^ sx) * 8))
#define QUAD1(N0)                                                             \
  __builtin_amdgcn_s_setprio(1);                                              \
  _Pragma("unroll") for (int m = 0; m < 4; ++m)                               \
  _Pragma("unroll") for (int n = 0; n < 2; ++n)                               \
  _Pragma("unroll") for (int ks = 0; ks < 2; ++ks)                            \
    acc[m][(N0) + n] = __builtin_amdgcn_mfma_f32_16x16x32_bf16(               \
        af[m][ks], bfr[n][ks], acc[m][(N0) + n], 0, 0, 0);                    \
  __builtin_amdgcn_s_setprio(0);

    // P0
    LDAF(0, 0); LDAF(0, 1); LDAF(1, 0); LDAF(1, 1);
    LDAF(2, 0); LDAF(2, 1); LDAF(3, 0); LDAF(3, 1);
    LDBF(0, 0, 0); LDBF(0, 0, 1); LDBF(1, 1, 0); LDBF(1, 1, 1);
    cfence();
    if (t + 1 < nt) STAGE_BH(t + 1, 0);
    bar(); QUAD1(0); bar();
    // P1
    LDBF(0, 2, 0); LDBF(0, 2, 1); LDBF(1, 3, 0); LDBF(1, 3, 1);
    cfence();
    if (t + 1 < nt) STAGE_BH(t + 1, 1);
    bar(); QUAD1(2); bar();
    // P2
    LDBF(0, 4, 0); LDBF(0, 4, 1); LDBF(1, 5, 0); LDBF(1, 5, 1);
    cfence();
    bar(); QUAD1(4); bar();
    // P3
    LDBF(0, 6, 0); LDBF(0, 6, 1); LDBF(1, 7, 0); LDBF(1, 7, 1);
    cfence();
    if (t + 1 < nt) {
      asm volatile("s_waitcnt vmcnt(8)" ::: "memory");
      WRITE_A();
      if (t + 2 < nt) {
        ISSUE_AV(t + 2);
        asm volatile("s_waitcnt vmcnt(4) lgkmcnt(0)" ::: "memory");
      } else {
        asm volatile("s_waitcnt vmcnt(0) lgkmcnt(0)" ::: "memory");
      }
    }
    __builtin_amdgcn_sched_barrier(0);
    bar(); QUAD1(6);
    if (t + 1 < nt) bar();

#undef LDAF
#undef LDBF
#undef QUAD1
  }
#undef ISSUE_AV
#undef WRITE_A
#undef STAGE_BH

  // epilogue: + bd/4, per-wave LDS transpose (Bsh[0] reuse), bf16x8 stores
  float bv[8];
#pragma unroll
  for (int n = 0; n < 8; ++n) bv[n] = 0.25f * bd[wnn + n * 16 + rl];

  float* scr = (float*)(&Bsh[0][0][0]) + wave * (16 * 128);
#pragma unroll
  for (int m = 0; m < 4; ++m) {
    int grow = bm + wm + m * 16;
#pragma unroll
    for (int n = 0; n < 8; ++n)
#pragma unroll
      for (int q = 0; q < 4; ++q)
        scr[(sw * 4 + q) * 128 + n * 16 + rl] = acc[m][n][q] + bv[n];
    asm volatile("s_waitcnt lgkmcnt(0)" ::: "memory");
#pragma unroll
    for (int p = 0; p < 4; ++p) {
      int row = p * 4 + sw;
      f32x4 a = *(const f32x4*)(scr + row * 128 + rl * 8);
      f32x4 b = *(const f32x4*)(scr + row * 128 + rl * 8 + 4);
      bf16x8 o;
#pragma unroll
      for (int e = 0; e < 4; ++e) { o[e] = f2b(a[e]); o[e + 4] = f2b(b[e]); }
      *(bf16x8*)(&Pc[(size_t)(grow + row) * NOUT + wnn + rl * 8]) = o;
    }
    asm volatile("s_waitcnt lgkmcnt(0)" ::: "memory");
  }
}

// ---------------------------------------------------------------------------
// GEMM2 with FUSED z-reduction: out = relu(Sum_c P_c) @ wuT^T + b_up -> f32.
// 256x256 tile, BK=64, nt=8, R9 8-phase structure.
// A-side: reg-staged reduce (4x bf16x8 loads per slot + f32 add + relu ->
//   swizzled ds_write), double-buffered; issued one tile ahead (counted vmcnt).
// B-side: gload_lds (unchanged from R9).
// vmcnt ledger/iter (per thread): in-flight at P3 = [A(t+1)x16, B(t+1)x4]
//   -> vmcnt(4) A landed; WRITE; ISSUE_A(t+2)x16 -> vmcnt(16) B landed. 
// XCD tiling: xcd owns rows [1024*xcd, +1024) = exactly the P slice its
//   gemm1f blocks wrote (L2-resident) x 8 col-tiles.
// ---------------------------------------------------------------------------
__global__ __launch_bounds__(512, 2)
void gemm2f(const bf16* __restrict__ P, const bf16* __restrict__ Bt,
            const float* __restrict__ bu, float* __restrict__ OUT) {
  constexpr int LDB = 512, N = 2048;
  __shared__ bf16 Ash[2][2][128 * 64];   // 64 KB
  __shared__ bf16 Bsh[2][2][128 * 64];   // 64 KB

  const int xcd = blockIdx.x & 7, w = blockIdx.x >> 3;
  const int bx = xcd * 4 + (w & 3);      // 0..31
  const int by = w >> 2;                 // 0..7
  const int bm = bx * 256;
  const int bn = by * 256;

  const int tid = threadIdx.x, lane = tid & 63, wave = tid >> 6;
  const int wmh = wave >> 2;
  const int wn2 = wave & 3;
  const int wnh = wn2 >> 1;
  const int brow = (wn2 & 1) * 64;
  const int rl = lane & 15, sw = lane >> 4, sx = rl & 7;

  // A reg-staging: thread -> row arow (0..255), 32 cols at ac0
  const int arow = tid >> 1, ac0 = (tid & 1) * 32;
  const int ah = arow >> 7, ar = arow & 127;
  const int as0 = (tid & 1) * 4;          // first of 4 16B slots
  const size_t CS = (size_t)8192 * 512;   // P chunk stride (elements)
  const bf16* __restrict__ Pr = P + (size_t)(bm + arow) * 512 + ac0;

  f32x4 acc[8][4] = {};
  bf16x8 avv[4][4];                       // [chunk][slot] in flight
  bf16x8 af[8][2], bf[4][2];

#define ISSUE_A(tt)                                                           \
  { _Pragma("unroll") for (int c = 0; c < 4; ++c)                             \
    _Pragma("unroll") for (int s = 0; s < 4; ++s)                             \
      avv[c][s] = *(const bf16x8*)(Pr + c * CS + (tt) * 64 + s * 8); }

#define WRITE_A(buf)                                                          \
  { _Pragma("unroll") for (int s = 0; s < 4; ++s) {                           \
      bf16x8 o;                                                               \
      _Pragma("unroll") for (int e = 0; e < 8; ++e) {                         \
        float v = b2f(avv[0][s][e]) + b2f(avv[1][s][e]) +                     \
                  b2f(avv[2][s][e]) + b2f(avv[3][s][e]);                      \
        o[e] = f2b(v > 0.f ? v : 0.f);                                        \
      }                                                                       \
      *(bf16x8*)(&Ash[buf][ah][ar * 64 + (((as0 + s) ^ (ar & 7)) * 8)]) = o;  \
    } }

#define STAGE_B(tt, h)                                                        \
  { _Pragma("unroll")                                                         \
    for (int is = 0; is < 2; ++is) {                                          \
      int idx = is * 512 + tid;                                               \
      int r = idx >> 3, sl = idx & 7;                                         \
      async16(Bt + (size_t)(bn + (h) * 128 + r) * LDB + (tt) * 64             \
                  + ((sl ^ (r & 7)) * 8),                                     \
              &Bsh[(tt) & 1][h][idx * 8]);                                    \
    } }

  const int nt = 8;

  // prologue
  ISSUE_A(0);
  asm volatile("s_waitcnt vmcnt(0)" ::: "memory");
  WRITE_A(0);
  STAGE_B(0, 0); STAGE_B(0, 1);
  ISSUE_A(1);
  asm volatile("s_waitcnt vmcnt(16) lgkmcnt(0)" ::: "memory");  // B(0) landed
  bar();

  for (int t = 0; t < nt; ++t) {
    const int cur = t & 1;
    const bf16* __restrict__ Acur = &Ash[cur][wmh][0];
    const bf16* __restrict__ Bcur = &Bsh[cur][wnh][0];

#define LDA_(m, ks) af[m][ks] = *(const bf16x8*)(Acur + ((m)*16 + rl) * 64 + ((((ks)*4 + sw) ^ sx) * 8))
#define LDB_(n, ks) bf[n][ks] = *(const bf16x8*)(Bcur + (brow + (n)*16 + rl) * 64 + ((((ks)*4 + sw) ^ sx) * 8))
#define QUAD2(M0, N0)                                                         \
  __builtin_amdgcn_s_setprio(1);                                              \
  _Pragma("unroll") for (int m = 0; m < 4; ++m)                               \
  _Pragma("unroll") for (int n = 0; n < 2; ++n)                               \
  _Pragma("unroll") for (int ks = 0; ks < 2; ++ks)                            \
    acc[(M0) + m][(N0) + n] = __builtin_amdgcn_mfma_f32_16x16x32_bf16(        \
        af[(M0) + m][ks], bf[(N0) + n][ks], acc[(M0) + m][(N0) + n], 0, 0, 0);\
  __builtin_amdgcn_s_setprio(0);

    // P0
    LDA_(0, 0); LDA_(0, 1); LDA_(1, 0); LDA_(1, 1);
    LDA_(2, 0); LDA_(2, 1); LDA_(3, 0); LDA_(3, 1);
    LDB_(0, 0); LDB_(0, 1); LDB_(1, 0); LDB_(1, 1);
    cfence();
    if (t + 1 < nt) STAGE_B(t + 1, 0);
    bar(); QUAD2(0, 0); bar();
    // P1
    LDB_(2, 0); LDB_(2, 1); LDB_(3, 0); LDB_(3, 1);
    cfence();
    if (t + 1 < nt) STAGE_B(t + 1, 1);
    bar(); QUAD2(0, 2); bar();
    // P2
    LDA_(4, 0); LDA_(4, 1); LDA_(5, 0); LDA_(5, 1);
    LDA_(6, 0); LDA_(6, 1); LDA_(7, 0); LDA_(7, 1);
    cfence();
    bar(); QUAD2(4, 0); bar();
    // P3: A(t+1) reduce+write, issue A(t+2); counted vmcnt
    if (t + 1 < nt) {
      asm volatile("s_waitcnt vmcnt(4)" ::: "memory");   // A(t+1) landed
      WRITE_A((t + 1) & 1);
      if (t + 2 < nt) {
        ISSUE_A(t + 2);
        asm volatile("s_waitcnt vmcnt(16) lgkmcnt(0)" ::: "memory"); // B(t+1)
      } else {
        asm volatile("s_waitcnt vmcnt(0) lgkmcnt(0)" ::: "memory");
      }
      __builtin_amdgcn_sched_barrier(0);
      bar();
    }
    QUAD2(4, 2);
    if (t + 1 < nt) bar();

#undef LDA_
#undef LDB_
#undef QUAD2
  }
#undef ISSUE_A
#undef WRITE_A
#undef STAGE_B

  // vectorized f32 epilogue: LDS transpose -> nontemporal f32x4 stores
  float* scr = (float*)(&Ash[0][0][0]) + wave * (16 * 68);
  const int r4 = lane >> 4;
  const int c4 = lane & 15;
#pragma unroll
  for (int m = 0; m < 8; ++m) {
    int grow = bm + wmh * 128 + m * 16;
#pragma unroll
    for (int n = 0; n < 4; ++n)
#pragma unroll
      for (int q = 0; q < 4; ++q)
        scr[(sw * 4 + q) * 68 + n * 16 + rl] =
            acc[m][n][q] + bu[bn + wn2 * 64 + n * 16 + rl];
    asm volatile("s_waitcnt lgkmcnt(0)" ::: "memory");
#pragma unroll
    for (int jj = 0; jj < 4; ++jj) {
      int row = jj * 4 + r4;
      f32x4 v = *(const f32x4*)(scr + row * 68 + c4 * 4);
      __builtin_nontemporal_store(
          v, (f32x4*)(&OUT[(size_t)(grow + row) * N + bn + wn2 * 64 + c4 * 4]));
    }
    asm volatile("s_waitcnt lgkmcnt(0)" ::: "memory");
  }
}

// ---------------------------------------------------------------------------
extern "C" void kernel_launch(void* const* d_in, const int* in_sizes, int n_in,
                              void* d_out, int out_size, void* d_ws, size_t ws_size,
                              hipStream_t stream) {
  const float* x      = (const float*)d_in[0];   // [8192,2048]
  const float* phm    = (const float*)d_in[1];   // [4,4,4]
  const float* W_down = (const float*)d_in[2];   // [4,512,128]
  const float* b_down = (const float*)d_in[3];   // [512]
  const float* W_up   = (const float*)d_in[4];   // [4,128,512]
  const float* b_up   = (const float*)d_in[5];   // [2048]
  float* out = (float*)d_out;                    // [8192,2048] f32

  const size_t MB = 1024 * 1024;
  char* ws = (char*)d_ws;
  bf16* wdT = (bf16*)(ws);                 //  2 MB  [512][2048]
  bf16* wuT = (bf16*)(ws + 2 * MB);        //  2 MB  [2048][512]
  bf16* P   = (bf16*)(ws + 4 * MB);        // 32 MB  4 x [8192][512] partials

  build_w<<<dim3((2 * 1024 * 1024) / 256), dim3(256), 0, stream>>>(
      phm, W_down, W_up, wdT, wuT);

  // P[ch] = x(f32) @ wdT (chunk ch) + bd/4, cast fused. grid 256
  gemm1f<<<dim3(256), dim3(512), 0, stream>>>(x, wdT, b_down, P);

  // out = relu(sum P) @ wuT + b_up, z-reduction fused. grid 256
  gemm2f<<<dim3(256), dim3(512), 0, stream>>>(P, wuT, b_up, out);
}

// Round 13
// 111.461 us; speedup vs baseline: 1.1874x; 1.1874x over previous
//
#include <hip/hip_runtime.h>
#include <hip/hip_bf16.h>
#include <stdint.h>

using bf16 = __hip_bfloat16;
typedef __attribute__((ext_vector_type(8))) short bf16x8;   // 8 bf16 = 4 VGPRs
typedef __attribute__((ext_vector_type(4))) float f32x4;

static __device__ __forceinline__ float b2f(short u) {
  union { float f; unsigned int i; } c;
  c.i = ((unsigned int)(unsigned short)u) << 16;
  return c.f;
}
static __device__ __forceinline__ short f2b(float f) {
  return (short)__bfloat16_as_ushort(__float2bfloat16(f));
}

static __device__ __forceinline__ void cfence() { asm volatile("" ::: "memory"); }
static __device__ __forceinline__ void bar()    { cfence(); __builtin_amdgcn_s_barrier(); cfence(); }

__device__ __forceinline__ void async16(const void* g, void* lds) {
  __builtin_amdgcn_global_load_lds(
      (const __attribute__((address_space(1))) void*)g,
      (__attribute__((address_space(3))) void*)lds, 16, 0, 0);
}

// ---------------------------------------------------------------------------
// Both Kron-expanded transposed weights in one dispatch.
// ---------------------------------------------------------------------------
__global__ void build_w(const float* __restrict__ phm,
                        const float* __restrict__ Wd,
                        const float* __restrict__ Wu,
                        bf16* __restrict__ wdT, bf16* __restrict__ wuT) {
  int idx = blockIdx.x * 256 + threadIdx.x;
  if (idx < 1024 * 1024) {
    int n = idx >> 11, k = idx & 2047;
    int r = n >> 7, s = n & 127;
    int p = k >> 9, q = k & 511;
    float v = 0.f;
#pragma unroll
    for (int i = 0; i < 4; ++i)
      v += phm[i * 16 + p * 4 + r] * Wd[i * 65536 + q * 128 + s];
    wdT[idx] = (bf16)v;
  } else {
    int jj = idx - 1024 * 1024;
    int d = jj >> 9, b = jj & 511;
    int r = d >> 9, s = d & 511;
    int p = b >> 7, q = b & 127;
    float v = 0.f;
#pragma unroll
    for (int i = 0; i < 4; ++i)
      v += phm[i * 16 + p * 4 + r] * Wu[i * 65536 + q * 512 + s];
    wuT[jj] = (bf16)v;
  }
}

// ---------------------------------------------------------------------------
// GEMM1 fused cast, split-K x4:  P[ch] = x(f32) @ wdT^T + bd/4
// BM=128, BN=512 (x read exactly ONCE), BK=64, chunk K=512. R9 structure.
// (byte-identical to R12's gemm1f)
// ---------------------------------------------------------------------------
__global__ __launch_bounds__(512, 2)
void gemm1f(const float* __restrict__ X, const bf16* __restrict__ Wt,
            const float* __restrict__ bd, bf16* __restrict__ P) {
  constexpr int BK = 64, KTOT = 2048, NOUT = 512;
  __shared__ bf16 Ash[128 * 64];          // 16 KB (single buffer)
  __shared__ bf16 Bsh[2][2][256 * 64];    // 128 KB

  const int xcd = blockIdx.x & 7, w = blockIdx.x >> 3;
  const int bx = xcd * 8 + (w & 7);       // 0..63 row tile
  const int ch = w >> 3;                  // 0..3 K chunk
  const int bm = bx * 128;
  const int koff = ch * 512;
  bf16* __restrict__ Pc = P + (size_t)ch * (8192 * NOUT);

  const int tid  = threadIdx.x;
  const int lane = tid & 63;
  const int wave = tid >> 6;
  const int wm   = (wave >> 2) * 64;
  const int wnn  = (wave & 3) * 128;
  const int hB   = wnn >> 8;
  const int bb   = wnn & 255;
  const int rl   = lane & 15;
  const int sw   = lane >> 4;
  const int sx   = rl & 7;

  const int arow = tid >> 2;
  const int ac0  = (tid & 3) * 16;
  const float* __restrict__ Xrow = X + (size_t)(bm + arow) * KTOT + koff + ac0;
  const int as0 = (tid & 3) * 2;

  f32x4 acc[4][8] = {};
  float4 av[4];

#define ISSUE_AV(tt)                                                          \
  { _Pragma("unroll")                                                         \
    for (int q = 0; q < 4; ++q)                                               \
      av[q] = *(const float4*)(Xrow + (size_t)(tt) * BK + q * 4); }

#define WRITE_A()                                                             \
  {                                                                           \
    bf16x8 w0, w1;                                                            \
    _Pragma("unroll")                                                         \
    for (int e = 0; e < 4; ++e) {                                             \
      w0[e]     = f2b(((const float*)&av[0])[e]);                             \
      w0[e + 4] = f2b(((const float*)&av[1])[e]);                             \
      w1[e]     = f2b(((const float*)&av[2])[e]);                             \
      w1[e + 4] = f2b(((const float*)&av[3])[e]);                             \
    }                                                                         \
    *(bf16x8*)(&Ash[arow * 64 + ((as0 ^ (arow & 7)) * 8)]) = w0;              \
    *(bf16x8*)(&Ash[arow * 64 + (((as0 + 1) ^ (arow & 7)) * 8)]) = w1;        \
  }

#define STAGE_BH(tt, h)                                                       \
  { _Pragma("unroll")                                                         \
    for (int is = 0; is < 4; ++is) {                                          \
      int idx = is * 512 + tid;                                               \
      int r = idx >> 3, sl = idx & 7;                                         \
      async16(Wt + (size_t)((h) * 256 + r) * KTOT + koff + (tt) * BK          \
                  + ((sl ^ (r & 7)) * 8),                                     \
              &Bsh[(tt) & 1][h][idx * 8]);                                    \
    } }

  const int nt = 512 / BK;   // 8

  ISSUE_AV(0);
  STAGE_BH(0, 0); STAGE_BH(0, 1);
  asm volatile("s_waitcnt vmcnt(8)" ::: "memory");
  WRITE_A();
  ISSUE_AV(1);
  asm volatile("s_waitcnt vmcnt(4) lgkmcnt(0)" ::: "memory");
  bar();

  bf16x8 af[4][2], bfr[2][2];

  for (int t = 0; t < nt; ++t) {
    const int cur = t & 1;
    const bf16* __restrict__ Bcur = &Bsh[cur][hB][0];

#define LDAF(m, ks) af[m][ks] = *(const bf16x8*)(&Ash[(wm + (m)*16 + rl) * 64 + ((((ks)*4 + sw) ^ sx) * 8)])
#define LDBF(q, n, ks) bfr[q][ks] = *(const bf16x8*)(Bcur + (bb + (n)*16 + rl) * 64 + ((((ks)*4 + sw) ^ sx) * 8))
#define QUAD1(N0)                                                             \
  __builtin_amdgcn_s_setprio(1);                                              \
  _Pragma("unroll") for (int m = 0; m < 4; ++m)                               \
  _Pragma("unroll") for (int n = 0; n < 2; ++n)                               \
  _Pragma("unroll") for (int ks = 0; ks < 2; ++ks)                            \
    acc[m][(N0) + n] = __builtin_amdgcn_mfma_f32_16x16x32_bf16(               \
        af[m][ks], bfr[n][ks], acc[m][(N0) + n], 0, 0, 0);                    \
  __builtin_amdgcn_s_setprio(0);

    // P0
    LDAF(0, 0); LDAF(0, 1); LDAF(1, 0); LDAF(1, 1);
    LDAF(2, 0); LDAF(2, 1); LDAF(3, 0); LDAF(3, 1);
    LDBF(0, 0, 0); LDBF(0, 0, 1); LDBF(1, 1, 0); LDBF(1, 1, 1);
    cfence();
    if (t + 1 < nt) STAGE_BH(t + 1, 0);
    bar(); QUAD1(0); bar();
    // P1
    LDBF(0, 2, 0); LDBF(0, 2, 1); LDBF(1, 3, 0); LDBF(1, 3, 1);
    cfence();
    if (t + 1 < nt) STAGE_BH(t + 1, 1);
    bar(); QUAD1(2); bar();
    // P2
    LDBF(0, 4, 0); LDBF(0, 4, 1); LDBF(1, 5, 0); LDBF(1, 5, 1);
    cfence();
    bar(); QUAD1(4); bar();
    // P3
    LDBF(0, 6, 0); LDBF(0, 6, 1); LDBF(1, 7, 0); LDBF(1, 7, 1);
    cfence();
    if (t + 1 < nt) {
      asm volatile("s_waitcnt vmcnt(8)" ::: "memory");
      WRITE_A();
      if (t + 2 < nt) {
        ISSUE_AV(t + 2);
        asm volatile("s_waitcnt vmcnt(4) lgkmcnt(0)" ::: "memory");
      } else {
        asm volatile("s_waitcnt vmcnt(0) lgkmcnt(0)" ::: "memory");
      }
    }
    __builtin_amdgcn_sched_barrier(0);
    bar(); QUAD1(6);
    if (t + 1 < nt) bar();

#undef LDAF
#undef LDBF
#undef QUAD1
  }
#undef ISSUE_AV
#undef WRITE_A
#undef STAGE_BH

  // epilogue: + bd/4, per-wave LDS transpose (Bsh[0] reuse), bf16x8 stores
  float bv[8];
#pragma unroll
  for (int n = 0; n < 8; ++n) bv[n] = 0.25f * bd[wnn + n * 16 + rl];

  float* scr = (float*)(&Bsh[0][0][0]) + wave * (16 * 128);
#pragma unroll
  for (int m = 0; m < 4; ++m) {
    int grow = bm + wm + m * 16;
#pragma unroll
    for (int n = 0; n < 8; ++n)
#pragma unroll
      for (int q = 0; q < 4; ++q)
        scr[(sw * 4 + q) * 128 + n * 16 + rl] = acc[m][n][q] + bv[n];
    asm volatile("s_waitcnt lgkmcnt(0)" ::: "memory");
#pragma unroll
    for (int p = 0; p < 4; ++p) {
      int row = p * 4 + sw;
      f32x4 a = *(const f32x4*)(scr + row * 128 + rl * 8);
      f32x4 b = *(const f32x4*)(scr + row * 128 + rl * 8 + 4);
      bf16x8 o;
#pragma unroll
      for (int e = 0; e < 4; ++e) { o[e] = f2b(a[e]); o[e + 4] = f2b(b[e]); }
      *(bf16x8*)(&Pc[(size_t)(grow + row) * NOUT + wnn + rl * 8]) = o;
    }
    asm volatile("s_waitcnt lgkmcnt(0)" ::: "memory");
  }
}

// ---------------------------------------------------------------------------
// GEMM2 fused z-reduce, SPILL-FREE: out = relu(Sum_c P_c) @ wuT^T + bu -> f32
// BM=128, BN=256, BK=64, nt=8. 8 waves (2M x 4N), per-wave 64x64 = acc[4][4].
// A: reg-staged reduce, 16 cols/thread -> avv[4][2] (32 VGPR only);
//    issued at P0 (one tile ahead), written at P3 after vmcnt(4).
// B: gload_lds, 2 halves at P0/P1 (as R9 gemm2).
// Ledger: issue order/tile = [A(t+1) x8, Bh0 x2, Bh1 x2].
//   P3: vmcnt(4) -> A landed (B in flight); end-P3: vmcnt(0) drains only the
//   3-phase-old B x4 (cheap).
// Registers: acc 64 + avv 32 + af 32 + bf 8 ~ 150 -> no scratch spill.
// XCD: xcd owns rows [xcd*1024,+1024) = its gemm1f P slice (L2) x 8 col-tiles.
// LDS 96KB; grid 512 (1 block/CU, 2 rounds).
// ---------------------------------------------------------------------------
__global__ __launch_bounds__(512, 2)
void gemm2f(const bf16* __restrict__ P, const bf16* __restrict__ Bt,
            const float* __restrict__ bu, float* __restrict__ OUT) {
  constexpr int LDB = 512, N = 2048;
  __shared__ bf16 Ash[2][128 * 64];      // 32 KB
  __shared__ bf16 Bsh[2][2][128 * 64];   // 64 KB

  const int xcd = blockIdx.x & 7, w = blockIdx.x >> 3;  // w 0..63
  const int bx = xcd * 8 + (w & 7);      // 0..63 row tile (128 rows)
  const int by = w >> 3;                 // 0..7 col tile (256 cols)
  const int bm = bx * 128, bn = by * 256;

  const int tid = threadIdx.x, lane = tid & 63, wave = tid >> 6;
  const int wm  = (wave >> 2) * 64;      // 2 M groups
  const int wn2 = wave & 3;              // 4 N groups of 64
  const int hB  = wn2 >> 1, brow = (wn2 & 1) * 64;
  const int rl = lane & 15, sw = lane >> 4, sx = rl & 7;

  // A staging: 128 rows x 64 cols; thread -> row tid>>2, 16 cols at (tid&3)*16
  const int arow = tid >> 2, as0 = (tid & 3) * 2;
  const size_t CS = (size_t)8192 * 512;
  const bf16* __restrict__ Pr = P + (size_t)(bm + arow) * 512 + (tid & 3) * 16;

  f32x4 acc[4][4] = {};
  bf16x8 avv[4][2];                      // 4 chunks x 2 slots in flight
  bf16x8 af[4][2], bf[2];

#define ISSUE_A(tt)                                                           \
  { _Pragma("unroll") for (int c = 0; c < 4; ++c)                             \
    _Pragma("unroll") for (int s = 0; s < 2; ++s)                             \
      avv[c][s] = *(const bf16x8*)(Pr + c * CS + (tt) * 64 + s * 8); }

#define WRITE_A(buf)                                                          \
  { _Pragma("unroll") for (int s = 0; s < 2; ++s) {                           \
      bf16x8 o;                                                               \
      _Pragma("unroll") for (int e = 0; e < 8; ++e) {                         \
        float v = b2f(avv[0][s][e]) + b2f(avv[1][s][e]) +                     \
                  b2f(avv[2][s][e]) + b2f(avv[3][s][e]);                      \
        o[e] = f2b(v > 0.f ? v : 0.f);                                        \
      }                                                                       \
      *(bf16x8*)(&Ash[buf][arow * 64 + (((as0 + s) ^ (arow & 7)) * 8)]) = o;  \
    } }

#define STAGE_B(tt, h)                                                        \
  { _Pragma("unroll")                                                         \
    for (int is = 0; is < 2; ++is) {                                          \
      int idx = is * 512 + tid;                                               \
      int r = idx >> 3, sl = idx & 7;                                         \
      async16(Bt + (size_t)(bn + (h) * 128 + r) * LDB + (tt) * 64             \
                  + ((sl ^ (r & 7)) * 8),                                     \
              &Bsh[(tt) & 1][h][idx * 8]);                                    \
    } }

  const int nt = 8;

  // prologue: A(0) reduce->LDS, B(0) staged
  ISSUE_A(0);
  asm volatile("s_waitcnt vmcnt(0)" ::: "memory");
  WRITE_A(0);
  STAGE_B(0, 0); STAGE_B(0, 1);
  asm volatile("s_waitcnt vmcnt(0) lgkmcnt(0)" ::: "memory");
  bar();

#define LDA_(m, ks) af[m][ks] = *(const bf16x8*)(&Ash[t & 1][(wm + (m)*16 + rl) * 64 + ((((ks)*4 + sw) ^ sx) * 8)])
#define LDB_(n, ks) bf[ks] = *(const bf16x8*)(&Bsh[t & 1][hB][(brow + (n)*16 + rl) * 64 + ((((ks)*4 + sw) ^ sx) * 8)])
#define QUADN(n)                                                              \
  __builtin_amdgcn_s_setprio(1);                                              \
  _Pragma("unroll") for (int m = 0; m < 4; ++m)                               \
  _Pragma("unroll") for (int ks = 0; ks < 2; ++ks)                            \
    acc[m][n] = __builtin_amdgcn_mfma_f32_16x16x32_bf16(                      \
        af[m][ks], bf[ks], acc[m][n], 0, 0, 0);                               \
  __builtin_amdgcn_s_setprio(0);

  for (int t = 0; t < nt; ++t) {
    // P0: all A-fragments + B n=0; issue A(t+1) then B(t+1) h0
    LDA_(0, 0); LDA_(0, 1); LDA_(1, 0); LDA_(1, 1);
    LDA_(2, 0); LDA_(2, 1); LDA_(3, 0); LDA_(3, 1);
    LDB_(0, 0); LDB_(0, 1);
    cfence();
    if (t + 1 < nt) { ISSUE_A(t + 1); STAGE_B(t + 1, 0); }
    cfence();
    bar(); QUADN(0); bar();
    // P1: B n=1; stage B(t+1) h1
    LDB_(1, 0); LDB_(1, 1);
    cfence();
    if (t + 1 < nt) STAGE_B(t + 1, 1);
    cfence();
    bar(); QUADN(1); bar();
    // P2: B n=2
    LDB_(2, 0); LDB_(2, 1);
    cfence();
    bar(); QUADN(2); bar();
    // P3: B n=3; A(t+1) landed -> reduce+write; end: drain B(t+1)
    LDB_(3, 0); LDB_(3, 1);
    cfence();
    if (t + 1 < nt) {
      asm volatile("s_waitcnt vmcnt(4)" ::: "memory");   // A(t+1) landed
      WRITE_A((t + 1) & 1);
    }
    asm volatile("s_waitcnt lgkmcnt(0)" ::: "memory");
    __builtin_amdgcn_sched_barrier(0);
    bar(); QUADN(3);
    if (t + 1 < nt) {
      asm volatile("s_waitcnt vmcnt(0)" ::: "memory");   // B(t+1) landed (old)
      bar();
    }
  }
#undef LDA_
#undef LDB_
#undef QUADN
#undef ISSUE_A
#undef WRITE_A
#undef STAGE_B

  // all LDS free after loop
  bar();

  // epilogue: per-wave 64x64 f32 transpose -> nontemporal f32x4 stores
  float* scr = (float*)(&Bsh[0][0][0]) + wave * (16 * 68);
  const int r4 = lane >> 4, c4 = lane & 15;
#pragma unroll
  for (int m = 0; m < 4; ++m) {
    int grow = bm + wm + m * 16;
#pragma unroll
    for (int n = 0; n < 4; ++n)
#pragma unroll
      for (int q = 0; q < 4; ++q)
        scr[(sw * 4 + q) * 68 + n * 16 + rl] =
            acc[m][n][q] + bu[bn + wn2 * 64 + n * 16 + rl];
    asm volatile("s_waitcnt lgkmcnt(0)" ::: "memory");
#pragma unroll
    for (int jj = 0; jj < 4; ++jj) {
      int row = jj * 4 + r4;
      f32x4 v = *(const f32x4*)(scr + row * 68 + c4 * 4);
      __builtin_nontemporal_store(
          v, (f32x4*)(&OUT[(size_t)(grow + row) * N + bn + wn2 * 64 + c4 * 4]));
    }
    asm volatile("s_waitcnt lgkmcnt(0)" ::: "memory");
  }
}

// ---------------------------------------------------------------------------
extern "C" void kernel_launch(void* const* d_in, const int* in_sizes, int n_in,
                              void* d_out, int out_size, void* d_ws, size_t ws_size,
                              hipStream_t stream) {
  const float* x      = (const float*)d_in[0];   // [8192,2048]
  const float* phm    = (const float*)d_in[1];   // [4,4,4]
  const float* W_down = (const float*)d_in[2];   // [4,512,128]
  const float* b_down = (const float*)d_in[3];   // [512]
  const float* W_up   = (const float*)d_in[4];   // [4,128,512]
  const float* b_up   = (const float*)d_in[5];   // [2048]
  float* out = (float*)d_out;                    // [8192,2048] f32

  const size_t MB = 1024 * 1024;
  char* ws = (char*)d_ws;
  bf16* wdT = (bf16*)(ws);                 //  2 MB  [512][2048]
  bf16* wuT = (bf16*)(ws + 2 * MB);        //  2 MB  [2048][512]
  bf16* P   = (bf16*)(ws + 4 * MB);        // 32 MB  4 x [8192][512] partials

  build_w<<<dim3((2 * 1024 * 1024) / 256), dim3(256), 0, stream>>>(
      phm, W_down, W_up, wdT, wuT);

  // P[ch] = x(f32) @ wdT (chunk ch) + bd/4, cast fused. grid 256
  gemm1f<<<dim3(256), dim3(512), 0, stream>>>(x, wdT, b_down, P);

  // out = relu(sum P) @ wuT + b_up, z-reduction fused. grid 512
  gemm2f<<<dim3(512), dim3(512), 0, stream>>>(P, wuT, b_up, out);
}

// Round 14
// 96.882 us; speedup vs baseline: 1.3661x; 1.1505x over previous
//
#include <hip/hip_runtime.h>
#include <hip/hip_bf16.h>
#include <stdint.h>

using bf16 = __hip_bfloat16;
typedef __attribute__((ext_vector_type(8))) short bf16x8;   // 8 bf16 = 4 VGPRs
typedef __attribute__((ext_vector_type(4))) float f32x4;

static __device__ __forceinline__ float b2f(short u) {
  union { float f; unsigned int i; } c;
  c.i = ((unsigned int)(unsigned short)u) << 16;
  return c.f;
}
static __device__ __forceinline__ short f2b(float f) {
  return (short)__bfloat16_as_ushort(__float2bfloat16(f));
}

static __device__ __forceinline__ void cfence() { asm volatile("" ::: "memory"); }
static __device__ __forceinline__ void bar()    { cfence(); __builtin_amdgcn_s_barrier(); cfence(); }

__device__ __forceinline__ void async16(const void* g, void* lds) {
  __builtin_amdgcn_global_load_lds(
      (const __attribute__((address_space(1))) void*)g,
      (__attribute__((address_space(3))) void*)lds, 16, 0, 0);
}

// ---------------------------------------------------------------------------
// Both Kron-expanded transposed weights in one dispatch.
// ---------------------------------------------------------------------------
__global__ void build_w(const float* __restrict__ phm,
                        const float* __restrict__ Wd,
                        const float* __restrict__ Wu,
                        bf16* __restrict__ wdT, bf16* __restrict__ wuT) {
  int idx = blockIdx.x * 256 + threadIdx.x;
  if (idx < 1024 * 1024) {
    int n = idx >> 11, k = idx & 2047;
    int r = n >> 7, s = n & 127;
    int p = k >> 9, q = k & 511;
    float v = 0.f;
#pragma unroll
    for (int i = 0; i < 4; ++i)
      v += phm[i * 16 + p * 4 + r] * Wd[i * 65536 + q * 128 + s];
    wdT[idx] = (bf16)v;
  } else {
    int j = idx - 1024 * 1024;
    int d = j >> 9, b = j & 511;
    int r = d >> 9, s = d & 511;
    int p = b >> 7, q = b & 127;
    float v = 0.f;
#pragma unroll
    for (int i = 0; i < 4; ++i)
      v += phm[i * 16 + p * 4 + r] * Wu[i * 65536 + q * 512 + s];
    wuT[j] = (bf16)v;
  }
}

// ---------------------------------------------------------------------------
// z = relu(sum_c P[c] + b_down) -> bf16.   P: 4 x [8192][512] bf16 partials
// ---------------------------------------------------------------------------
__global__ void zred(const bf16* __restrict__ P, const float* __restrict__ bias,
                     bf16* __restrict__ z) {
  int i = blockIdx.x * 256 + threadIdx.x;
  const int NV = 8192 * 512 / 8;
  if (i >= NV) return;
  const size_t CS = (size_t)NV;
  bf16x8 v0 = ((const bf16x8*)P)[i];
  bf16x8 v1 = ((const bf16x8*)P)[i + CS];
  bf16x8 v2 = ((const bf16x8*)P)[i + 2 * CS];
  bf16x8 v3 = ((const bf16x8*)P)[i + 3 * CS];
  int c0 = (i * 8) & 511;
  bf16x8 o;
#pragma unroll
  for (int j = 0; j < 8; ++j) {
    float t = b2f(v0[j]) + b2f(v1[j]) + b2f(v2[j]) + b2f(v3[j]) + bias[c0 + j];
    o[j] = f2b(t > 0.f ? t : 0.f);
  }
  ((bf16x8*)z)[i] = o;
}

// ---------------------------------------------------------------------------
// GEMM1 fused cast, split-K x4:  P[c] = x(f32)[.][c-chunk] @ wdT^T
// BM=128, BN=512 (x read exactly ONCE), BK=64, chunk K=512.
// 8 waves (2M x 4N), per-wave 64x128 = acc[4][8].
// A: reg-staged f32->bf16 (single LDS buffer); B: gload_lds double-buffered.
// Epilogue: per-wave LDS transpose (Bsh[0] reuse) -> contiguous bf16x8 stores.
// XCD tiling: xcd=bid&7 owns 8 row tiles x 4 chunks (wdT L2-resident).
// ---------------------------------------------------------------------------
__global__ __launch_bounds__(512, 2)
void gemm1f(const float* __restrict__ X, const bf16* __restrict__ Wt,
            bf16* __restrict__ P) {
  constexpr int BK = 64, KTOT = 2048, NOUT = 512;
  __shared__ bf16 Ash[128 * 64];          // 16 KB (single buffer)
  __shared__ bf16 Bsh[2][2][256 * 64];    // 128 KB

  const int xcd = blockIdx.x & 7, w = blockIdx.x >> 3;
  const int bx = xcd * 8 + (w & 7);       // 0..63 row tile
  const int ch = w >> 3;                  // 0..3 K chunk
  const int bm = bx * 128;
  const int koff = ch * 512;
  bf16* __restrict__ Pc = P + (size_t)ch * (8192 * NOUT);

  const int tid  = threadIdx.x;           // 0..511
  const int lane = tid & 63;
  const int wave = tid >> 6;
  const int wm   = (wave >> 2) * 64;      // 2 M groups
  const int wnn  = (wave & 3) * 128;      // 4 N groups of 128
  const int hB   = wnn >> 8;              // B half
  const int bb   = wnn & 255;             // row base within half (0 or 128)
  const int rl   = lane & 15;
  const int sw   = lane >> 4;
  const int sx   = rl & 7;

  const int arow = tid >> 2;
  const int ac0  = (tid & 3) * 16;
  const float* __restrict__ Xrow = X + (size_t)(bm + arow) * KTOT + koff + ac0;
  const int as0 = (tid & 3) * 2;

  f32x4 acc[4][8] = {};
  float4 av[4];

#define ISSUE_AV(tt)                                                          \
  { _Pragma("unroll")                                                         \
    for (int q = 0; q < 4; ++q)                                               \
      av[q] = *(const float4*)(Xrow + (size_t)(tt) * BK + q * 4); }

#define WRITE_A()                                                             \
  {                                                                           \
    bf16x8 w0, w1;                                                            \
    _Pragma("unroll")                                                         \
    for (int e = 0; e < 4; ++e) {                                             \
      w0[e]     = f2b(((const float*)&av[0])[e]);                             \
      w0[e + 4] = f2b(((const float*)&av[1])[e]);                             \
      w1[e]     = f2b(((const float*)&av[2])[e]);                             \
      w1[e + 4] = f2b(((const float*)&av[3])[e]);                             \
    }                                                                         \
    *(bf16x8*)(&Ash[arow * 64 + ((as0 ^ (arow & 7)) * 8)]) = w0;              \
    *(bf16x8*)(&Ash[arow * 64 + (((as0 + 1) ^ (arow & 7)) * 8)]) = w1;        \
  }

#define STAGE_BH(tt, h)                                                       \
  { _Pragma("unroll")                                                         \
    for (int is = 0; is < 4; ++is) {                                          \
      int idx = is * 512 + tid;                                               \
      int r = idx >> 3, sl = idx & 7;                                         \
      async16(Wt + (size_t)((h) * 256 + r) * KTOT + koff + (tt) * BK          \
                  + ((sl ^ (r & 7)) * 8),                                     \
              &Bsh[(tt) & 1][h][idx * 8]);                                    \
    } }

  const int nt = 512 / BK;   // 8

  // prologue
  ISSUE_AV(0);
  STAGE_BH(0, 0); STAGE_BH(0, 1);
  asm volatile("s_waitcnt vmcnt(8)" ::: "memory");   // Av(0) landed
  WRITE_A();
  ISSUE_AV(1);
  asm volatile("s_waitcnt vmcnt(4) lgkmcnt(0)" ::: "memory");  // B(0) landed
  bar();

  bf16x8 af[4][2], bfr[2][2];

  for (int t = 0; t < nt; ++t) {
    const int cur = t & 1;
    const bf16* __restrict__ Bcur = &Bsh[cur][hB][0];

#define LDAF(m, ks) af[m][ks] = *(const bf16x8*)(&Ash[(wm + (m)*16 + rl) * 64 + ((((ks)*4 + sw) ^ sx) * 8)])
#define LDBF(j, n, ks) bfr[j][ks] = *(const bf16x8*)(Bcur + (bb + (n)*16 + rl) * 64 + ((((ks)*4 + sw) ^ sx) * 8))
#define QUAD(N0)                                                              \
  __builtin_amdgcn_s_setprio(1);                                              \
  _Pragma("unroll") for (int m = 0; m < 4; ++m)                               \
  _Pragma("unroll") for (int n = 0; n < 2; ++n)                               \
  _Pragma("unroll") for (int ks = 0; ks < 2; ++ks)                            \
    acc[m][(N0) + n] = __builtin_amdgcn_mfma_f32_16x16x32_bf16(               \
        af[m][ks], bfr[n][ks], acc[m][(N0) + n], 0, 0, 0);                    \
  __builtin_amdgcn_s_setprio(0);

    // P0
    LDAF(0, 0); LDAF(0, 1); LDAF(1, 0); LDAF(1, 1);
    LDAF(2, 0); LDAF(2, 1); LDAF(3, 0); LDAF(3, 1);
    LDBF(0, 0, 0); LDBF(0, 0, 1); LDBF(1, 1, 0); LDBF(1, 1, 1);
    cfence();
    if (t + 1 < nt) STAGE_BH(t + 1, 0);
    bar(); QUAD(0); bar();
    // P1
    LDBF(0, 2, 0); LDBF(0, 2, 1); LDBF(1, 3, 0); LDBF(1, 3, 1);
    cfence();
    if (t + 1 < nt) STAGE_BH(t + 1, 1);
    bar(); QUAD(2); bar();
    // P2
    LDBF(0, 4, 0); LDBF(0, 4, 1); LDBF(1, 5, 0); LDBF(1, 5, 1);
    cfence();
    bar(); QUAD(4); bar();
    // P3
    LDBF(0, 6, 0); LDBF(0, 6, 1); LDBF(1, 7, 0); LDBF(1, 7, 1);
    cfence();
    if (t + 1 < nt) {
      asm volatile("s_waitcnt vmcnt(8)" ::: "memory");   // Av(t+1) landed
      WRITE_A();
      if (t + 2 < nt) {
        ISSUE_AV(t + 2);
        asm volatile("s_waitcnt vmcnt(4) lgkmcnt(0)" ::: "memory");
      } else {
        asm volatile("s_waitcnt vmcnt(0) lgkmcnt(0)" ::: "memory");
      }
    }
    __builtin_amdgcn_sched_barrier(0);
    bar(); QUAD(6);
    if (t + 1 < nt) bar();

#undef LDAF
#undef LDBF
#undef QUAD
  }
#undef ISSUE_AV
#undef WRITE_A
#undef STAGE_BH

  // ---- vectorized epilogue: per-wave LDS transpose -> bf16x8 stores ----
  float* scr = (float*)(&Bsh[0][0][0]) + wave * (16 * 128);
#pragma unroll
  for (int m = 0; m < 4; ++m) {
    int grow = bm + wm + m * 16;
#pragma unroll
    for (int n = 0; n < 8; ++n)
#pragma unroll
      for (int j = 0; j < 4; ++j)
        scr[(sw * 4 + j) * 128 + n * 16 + rl] = acc[m][n][j];
    asm volatile("s_waitcnt lgkmcnt(0)" ::: "memory");
#pragma unroll
    for (int p = 0; p < 4; ++p) {
      int row = p * 4 + sw;
      f32x4 a = *(const f32x4*)(scr + row * 128 + rl * 8);
      f32x4 b = *(const f32x4*)(scr + row * 128 + rl * 8 + 4);
      bf16x8 o;
#pragma unroll
      for (int e = 0; e < 4; ++e) { o[e] = f2b(a[e]); o[e + 4] = f2b(b[e]); }
      *(bf16x8*)(&Pc[(size_t)(grow + row) * NOUT + wnn + rl * 8]) = o;
    }
    asm volatile("s_waitcnt lgkmcnt(0)" ::: "memory");
  }
}

// ---------------------------------------------------------------------------
// GEMM2: 8-phase 256x256, BK=64.  out = z @ wuT^T + b_up -> f32
// XCD tiling: xcd owns 4 row-tiles x 8 col-tiles (z panel 1MB + wuT 2MB in L2)
// Epilogue: per-wave LDS transpose -> nontemporal f32x4 stores.
// ---------------------------------------------------------------------------
__global__ __launch_bounds__(512, 2)
void gemm2(const bf16* __restrict__ A, const bf16* __restrict__ Bt,
           const float* __restrict__ bias, float* __restrict__ Cout) {
  constexpr int BK = 64, LDA = 512, LDB = 512, N = 2048;
  __shared__ bf16 Ash[2][2][128 * 64];   // 64 KB
  __shared__ bf16 Bsh[2][2][128 * 64];   // 64 KB

  const int xcd = blockIdx.x & 7, w = blockIdx.x >> 3;
  const int bx = xcd * 4 + (w & 3);      // 0..31
  const int by = w >> 2;                 // 0..7
  const int bm = bx * 256;
  const int bn = by * 256;

  const int tid  = threadIdx.x;
  const int lane = tid & 63;
  const int wave = tid >> 6;
  const int wmh  = wave >> 2;
  const int wn   = wave & 3;
  const int wnh  = wn >> 1;
  const int brow = (wn & 1) * 64;
  const int rl   = lane & 15;
  const int sw   = lane >> 4;
  const int sx   = rl & 7;

  f32x4 acc[8][4] = {};

#define STAGE_A(tt, h)                                                        \
  { _Pragma("unroll")                                                         \
    for (int is = 0; is < 2; ++is) {                                          \
      int idx = is * 512 + tid;                                               \
      int r = idx >> 3, sl = idx & 7;                                         \
      async16(A + (size_t)(bm + (h) * 128 + r) * LDA + (tt) * BK              \
                  + ((sl ^ (r & 7)) * 8),                                     \
              &Ash[(tt) & 1][h][idx * 8]);                                    \
    } }
#define STAGE_B(tt, h)                                                        \
  { _Pragma("unroll")                                                         \
    for (int is = 0; is < 2; ++is) {                                          \
      int idx = is * 512 + tid;                                               \
      int r = idx >> 3, sl = idx & 7;                                         \
      async16(Bt + (size_t)(bn + (h) * 128 + r) * LDB + (tt) * BK             \
                  + ((sl ^ (r & 7)) * 8),                                     \
              &Bsh[(tt) & 1][h][idx * 8]);                                    \
    } }

  const int nt = 512 / BK;   // 8

  STAGE_A(0, 0); STAGE_A(0, 1);
  STAGE_B(0, 0); STAGE_B(0, 1);
  STAGE_A(1, 0); STAGE_A(1, 1);
  asm volatile("s_waitcnt vmcnt(4)" ::: "memory");
  bar();

  bf16x8 af[8][2], bf[4][2];

  for (int t = 0; t < nt; ++t) {
    const int cur = t & 1;
    const bf16* __restrict__ Acur = &Ash[cur][wmh][0];
    const bf16* __restrict__ Bcur = &Bsh[cur][wnh][0];

#define LDA_(m, ks) af[m][ks] = *(const bf16x8*)(Acur + ((m)*16 + rl) * 64 + ((((ks)*4 + sw) ^ sx) * 8))
#define LDB_(n, ks) bf[n][ks] = *(const bf16x8*)(Bcur + (brow + (n)*16 + rl) * 64 + ((((ks)*4 + sw) ^ sx) * 8))
#define QUAD(M0, N0)                                                          \
  __builtin_amdgcn_s_setprio(1);                                              \
  _Pragma("unroll") for (int m = 0; m < 4; ++m)                               \
  _Pragma("unroll") for (int n = 0; n < 2; ++n)                               \
  _Pragma("unroll") for (int ks = 0; ks < 2; ++ks)                            \
    acc[(M0) + m][(N0) + n] = __builtin_amdgcn_mfma_f32_16x16x32_bf16(        \
        af[(M0) + m][ks], bf[(N0) + n][ks], acc[(M0) + m][(N0) + n], 0, 0, 0);\
  __builtin_amdgcn_s_setprio(0);

    // P0
    LDA_(0, 0); LDA_(0, 1); LDA_(1, 0); LDA_(1, 1);
    LDA_(2, 0); LDA_(2, 1); LDA_(3, 0); LDA_(3, 1);
    LDB_(0, 0); LDB_(0, 1); LDB_(1, 0); LDB_(1, 1);
    cfence();
    if (t + 1 < nt) STAGE_B(t + 1, 0);
    bar(); QUAD(0, 0); bar();
    // P1
    LDB_(2, 0); LDB_(2, 1); LDB_(3, 0); LDB_(3, 1);
    cfence();
    if (t + 1 < nt) STAGE_B(t + 1, 1);
    bar(); QUAD(0, 2); bar();
    // P2
    LDA_(4, 0); LDA_(4, 1); LDA_(5, 0); LDA_(5, 1);
    LDA_(6, 0); LDA_(6, 1); LDA_(7, 0); LDA_(7, 1);
    cfence();
    bar(); QUAD(4, 0); bar();
    // P3
    if (t + 2 < nt) {
      STAGE_A(t + 2, 0); STAGE_A(t + 2, 1);
      asm volatile("s_waitcnt vmcnt(4)" ::: "memory");
    } else if (t + 1 < nt) {
      asm volatile("s_waitcnt vmcnt(0)" ::: "memory");
    }
    bar(); QUAD(4, 2);
    if (t + 1 < nt) bar();

#undef LDA_
#undef LDB_
#undef QUAD
  }
#undef STAGE_A
#undef STAGE_B

  // ---- vectorized epilogue: LDS transpose -> nontemporal f32x4 stores ----
  float* scr = (float*)(&Ash[0][0][0]) + wave * (16 * 68);
  const int r4 = lane >> 4;        // 0..3
  const int c4 = lane & 15;        // 0..15
#pragma unroll
  for (int m = 0; m < 8; ++m) {
    int grow = bm + wmh * 128 + m * 16;
#pragma unroll
    for (int n = 0; n < 4; ++n)
#pragma unroll
      for (int j = 0; j < 4; ++j)
        scr[(sw * 4 + j) * 68 + n * 16 + rl] = acc[m][n][j] + bias[bn + wn * 64 + n * 16 + rl];
    asm volatile("s_waitcnt lgkmcnt(0)" ::: "memory");
#pragma unroll
    for (int jj = 0; jj < 4; ++jj) {
      int row = jj * 4 + r4;
      f32x4 v = *(const f32x4*)(scr + row * 68 + c4 * 4);
      __builtin_nontemporal_store(
          v, (f32x4*)(&Cout[(size_t)(grow + row) * N + bn + wn * 64 + c4 * 4]));
    }
    asm volatile("s_waitcnt lgkmcnt(0)" ::: "memory");
  }
}

// ---------------------------------------------------------------------------
extern "C" void kernel_launch(void* const* d_in, const int* in_sizes, int n_in,
                              void* d_out, int out_size, void* d_ws, size_t ws_size,
                              hipStream_t stream) {
  const float* x      = (const float*)d_in[0];   // [8192,2048]
  const float* phm    = (const float*)d_in[1];   // [4,4,4]
  const float* W_down = (const float*)d_in[2];   // [4,512,128]
  const float* b_down = (const float*)d_in[3];   // [512]
  const float* W_up   = (const float*)d_in[4];   // [4,128,512]
  const float* b_up   = (const float*)d_in[5];   // [2048]
  float* out = (float*)d_out;                    // [8192,2048] f32

  const int T = 8192, B = 512;
  const size_t MB = 1024 * 1024;

  char* ws = (char*)d_ws;
  bf16* wdT = (bf16*)(ws);                 //  2 MB  [512][2048]
  bf16* wuT = (bf16*)(ws + 2 * MB);        //  2 MB  [2048][512]
  bf16* z   = (bf16*)(ws + 4 * MB);        //  8 MB  [8192][512]
  bf16* P   = (bf16*)(ws + 12 * MB);       // 32 MB  4 x [8192][512] partials

  build_w<<<dim3((2 * 1024 * 1024) / 256), dim3(256), 0, stream>>>(
      phm, W_down, W_up, wdT, wuT);

  // P[c] = x(f32) @ wdT (chunk c), cast fused, x read once. grid 256
  gemm1f<<<dim3(256), dim3(512), 0, stream>>>(x, wdT, P);

  // z = relu(sum P + b_down)
  zred<<<dim3(T * B / 8 / 256), dim3(256), 0, stream>>>(P, b_down, z);

  // out = z @ wuT + b_up. grid 256
  gemm2<<<dim3(256), dim3(512), 0, stream>>>(z, wuT, b_up, out);
}